// Round 8
// baseline (381.038 us; speedup 1.0000x reference)
//
#include <hip/hip_runtime.h>
#include <hip/hip_fp16.h>

#define BTHREADS 256
#define CHUNK 7936       // edges per chunk_sort_flush block (31 KB LDS staging)
#define BB 11            // bucket bits: 2048 nodes per bucket
#define BSZ (1 << BB)
#define BMASK (BSZ - 1)
#define MAXNB 512        // max dst-buckets (N <= 1,048,576)
#define SLICES 4         // src slices (xs slice = 2 MB -> per-XCD L2-resident)
#define SSHIFT 18        // src slice = src >> 18 (N <= 2^20)
#define MAXNKEY 2048     // max (bucket,slice) keys
#define S2T 512          // sort2 threads
#define SCAP 4608        // LDS staging cap per key (~mean 4090 + 8 sigma)
#define CP(i) ((i) + ((i) >> 5))   // +1-per-32 pad: breaks LDS bank conflicts

// ---------------- helpers ----------------
__device__ __forceinline__ int detect64(const int* __restrict__ ei) {
    return (ei[1] | ei[3] | ei[5] | ei[7] | ei[9] | ei[11] | ei[13] | ei[15]) == 0;
}
__device__ __forceinline__ int load_src(const int* __restrict__ ei, int e, int is64) {
    return is64 ? ei[2 * (size_t)e] : ei[(size_t)e];
}
__device__ __forceinline__ int load_dst(const int* __restrict__ ei, int E, int e, int is64) {
    return is64 ? ei[2 * ((size_t)E + e)] : ei[(size_t)E + e];
}
__device__ __forceinline__ unsigned int h2u(__half2 h) {
    union { __half2 h; unsigned int u; } c; c.h = h; return c.u;
}
__device__ __forceinline__ __half2 u2h(unsigned int u) {
    union { __half2 h; unsigned int u; } c; c.u = u; return c.h;
}

// Init per-key cursors to static region bases (no pre-histogram needed).
__global__ __launch_bounds__(256) void init_cur(
    unsigned int* __restrict__ gcur, int NKEY, unsigned int capk) {
    int k = blockIdx.x * 256 + threadIdx.x;
    if (k < NKEY) gcur[k] = (unsigned int)k * capk;
}

// chunk_sort_flush: LDS-sort one 7936-edge chunk by 13-bit (bucket,slice) key,
// reserve per-key space in padded global ebin (one atomicAdd per (chunk,key);
// open tail-lines = NKEY*64B = 122 KB, L2-resident), flush with FULL lanes via
// per-element binary search (j -> key) -- no short-run lane idling.
__global__ __launch_bounds__(BTHREADS) void chunk_sort_flush(
    const int* __restrict__ ei, int E, int NKEY,
    unsigned int* __restrict__ gcur, unsigned int* __restrict__ ebin,
    unsigned int total_cap) {
    __shared__ unsigned int cnt[MAXNKEY];    // counts -> starts -> (post-scatter) ends
    __shared__ unsigned int ssum[BTHREADS];
    __shared__ unsigned int stg[CHUNK];      // 31 KB
    __shared__ unsigned int gdst[MAXNKEY];   // reserved_base - local_start (wrap ok)
    int t = threadIdx.x, blk = blockIdx.x;
    for (int u = t; u < MAXNKEY; u += BTHREADS) cnt[u] = 0;
    __syncthreads();
    int is64 = detect64(ei);
    int lo = blk * CHUNK;
    int hi = lo + CHUNK; if (hi > E) hi = E;
    int n = hi - lo;
    for (int e = lo + t; e < hi; e += BTHREADS) {
        int s = load_src(ei, e, is64);
        int d = load_dst(ei, E, e, is64);
        int key = ((d >> BB) << 2) | (s >> SSHIFT);
        atomicAdd(&cnt[key], 1u);
    }
    __syncthreads();
    // exclusive scan over 2048 counters: 8 contiguous per thread + block scan
    unsigned int v[8];
    unsigned int sum = 0;
#pragma unroll
    for (int j = 0; j < 8; ++j) { unsigned int c = cnt[8 * t + j]; v[j] = sum; sum += c; }
    ssum[t] = sum;
    __syncthreads();
    for (int o = 1; o < BTHREADS; o <<= 1) {
        unsigned int x2 = (t >= o) ? ssum[t - o] : 0;
        __syncthreads();
        ssum[t] += x2;
        __syncthreads();
    }
    unsigned int base = t ? ssum[t - 1] : 0;
#pragma unroll
    for (int j = 0; j < 8; ++j) cnt[8 * t + j] = base + v[j];
    __syncthreads();
    // scatter into LDS staging (LDS absorbs the scatter at bank granularity)
    for (int e = lo + t; e < hi; e += BTHREADS) {
        int s = load_src(ei, e, is64);
        int d = load_dst(ei, E, e, is64);
        int key = ((d >> BB) << 2) | (s >> SSHIFT);
        unsigned int pos = atomicAdd(&cnt[key], 1u);
        stg[pos] = ((unsigned int)s << BB) | (unsigned int)(d & BMASK);
    }
    __syncthreads();
    // reserve: post-scatter invariant cnt[u] == end(u); start(u) == (u?cnt[u-1]:0)
    for (int u = t; u < NKEY; u += BTHREADS) {
        unsigned int lst = u ? cnt[u - 1] : 0;
        unsigned int L = cnt[u] - lst;
        if (L) gdst[u] = atomicAdd(&gcur[u], L) - lst;
    }
    __syncthreads();
    // full-lane flush: binary search j -> key over ends (11 LDS reads, mostly
    // broadcast since adjacent j share the key)
    for (int j = t; j < n; j += BTHREADS) {
        int lo2 = 0, hi2 = NKEY - 1;
        while (lo2 < hi2) {
            int mid = (lo2 + hi2) >> 1;
            if (cnt[mid] > (unsigned int)j) hi2 = mid; else lo2 = mid + 1;
        }
        unsigned int gpos = gdst[lo2] + (unsigned int)j;
        if (gpos < total_cap) ebin[gpos] = stg[j];
    }
}

// Per (bucket,slice) key: contiguous read of its padded ebin region, 11-bit
// counting sort by dstlow staged in LDS, coalesced flush to ebin2 (src ids),
// u16 row offsets rp16. 28 KB LDS -> 4 blocks/CU (balanced, no 2x tail).
__global__ __launch_bounds__(S2T) void sort2(
    const unsigned int* __restrict__ ebin, const unsigned int* __restrict__ gcur,
    unsigned int* __restrict__ ebin2, unsigned short* __restrict__ rp16,
    unsigned int capk) {
    __shared__ unsigned int cnt[CP(BSZ)];   // 8.4 KB, bank-padded
    __shared__ unsigned int ssum[S2T];      // 2 KB
    __shared__ unsigned int stg2[SCAP];     // 18 KB
    int k = blockIdx.x, t = threadIdx.x;
    for (int j = t; j < CP(BSZ); j += S2T) cnt[j] = 0;
    __syncthreads();
    unsigned int kb = (unsigned int)k * capk;
    unsigned int ne_raw = gcur[k] - kb;
    int ne = (int)(ne_raw < capk ? ne_raw : capk);
    // count phase: contiguous coalesced read
    for (int i = t; i < ne; i += S2T) {
        unsigned int k11 = ebin[kb + i] & BMASK;
        atomicAdd(&cnt[CP(k11)], 1u);
    }
    __syncthreads();
    // exclusive scan of 2048 counters: 4 contiguous per thread + block scan
    unsigned int loc[4];
    unsigned int s = 0;
#pragma unroll
    for (int j = 0; j < 4; ++j) { loc[j] = s; s += cnt[CP(4 * t + j)]; }
    ssum[t] = s;
    __syncthreads();
    for (int o = 1; o < S2T; o <<= 1) {
        unsigned int v = (t >= o) ? ssum[t - o] : 0;
        __syncthreads();
        ssum[t] += v;
        __syncthreads();
    }
    unsigned int tb = t ? ssum[t - 1] : 0;
    size_t rb = (size_t)k * BSZ;
#pragma unroll
    for (int j = 0; j < 4; ++j)
        rp16[rb + 4 * t + j] = (unsigned short)(tb + loc[j]);
#pragma unroll
    for (int j = 0; j < 4; ++j) cnt[CP(4 * t + j)] = tb + loc[j];
    __syncthreads();
    // scatter phase: re-read (L2-hot), scatter src ids into LDS staging
    for (int i = t; i < ne; i += S2T) {
        unsigned int rec = ebin[kb + i];
        unsigned int pos = atomicAdd(&cnt[CP(rec & BMASK)], 1u);
        unsigned int v = rec >> BB;   // src node id
        if (pos < SCAP) stg2[pos] = v;
        else ebin2[kb + pos] = v;     // overflow fallback (memory-safe, ~never)
    }
    __syncthreads();
    // coalesced flush to ebin2
    int m = ne < SCAP ? ne : SCAP;
    for (int j = t; j < m; j += S2T) ebin2[kb + j] = stg2[j];
}

// Node-parallel: degree from rp16 run-length differences (4 slices) -> dinv,
// xs = half4(x * dinv).
__global__ __launch_bounds__(256) void deg_prep(
    const unsigned short* __restrict__ rp16, const unsigned int* __restrict__ gcur,
    const float4* __restrict__ x, float* __restrict__ dinv, uint2* __restrict__ xs,
    int N, unsigned int capk) {
    int g = blockIdx.x * 256 + threadIdx.x;
    if (g >= N) return;
    int b = g >> BB, j = g & BMASK;
    unsigned int deg = 0;
#pragma unroll
    for (int s = 0; s < SLICES; ++s) {
        int key = (b << 2) | s;
        size_t rb = (size_t)key * BSZ;
        unsigned int st = rp16[rb + j];
        unsigned int en;
        if (j == BMASK) {
            unsigned int ner = gcur[key] - (unsigned int)key * capk;
            en = ner < capk ? ner : capk;
        } else en = rp16[rb + j + 1];
        deg += en - st;
    }
    float di = rsqrtf((float)(deg + 1u));
    dinv[g] = di;
    float4 v = x[g];
    uint2 p;
    p.x = h2u(__halves2half2(__float2half_rn(v.x * di), __float2half_rn(v.y * di)));
    p.y = h2u(__halves2half2(__float2half_rn(v.z * di), __float2half_rn(v.w * di)));
    xs[g] = p;
}

// Block remap: bid%8 determines XCD (round-robin dispatch); pin slice = (bid&3)
// so each XCD's gather working set is ONE 2 MB slice (round-2-proven mapping).
__global__ __launch_bounds__(256) void l1_gather(
    const unsigned int* __restrict__ ebin2, const unsigned short* __restrict__ rp16,
    const unsigned int* __restrict__ gcur, const uint2* __restrict__ xs,
    float4* __restrict__ partial, unsigned int capk) {
    int bid = blockIdx.x, t = threadIdx.x;
    int r = bid & 7, s = r & 3, half = r >> 2, q = bid >> 3;
    int b = q >> 2, sub = (half << 2) | (q & 3);
    int key = (b << 2) | s;
    int idx = (key << BB) + (sub << 8) + t;
    unsigned int kb = (unsigned int)key * capk;
    unsigned int st = kb + rp16[idx];
    unsigned int en;
    if ((sub == 7) && (t == 255)) {           // last node of this key's region
        unsigned int ner = gcur[key] - kb;
        en = kb + (ner < capk ? ner : capk);
    } else en = kb + rp16[idx + 1];
    float ax = 0.0f, ay = 0.0f, az = 0.0f, aw = 0.0f;
    unsigned int e = st;
    for (; e + 2 <= en; e += 2) {
        unsigned int s0 = ebin2[e], s1 = ebin2[e + 1];
        uint2 r0 = xs[s0], r1 = xs[s1];
        __half2 a01 = u2h(r0.x), a23 = u2h(r0.y);
        __half2 b01 = u2h(r1.x), b23 = u2h(r1.y);
        ax += __half2float(__low2half(a01)) + __half2float(__low2half(b01));
        ay += __half2float(__high2half(a01)) + __half2float(__high2half(b01));
        az += __half2float(__low2half(a23)) + __half2float(__low2half(b23));
        aw += __half2float(__high2half(a23)) + __half2float(__high2half(b23));
    }
    if (e < en) {
        uint2 rr = xs[ebin2[e]];
        __half2 a01 = u2h(rr.x), a23 = u2h(rr.y);
        ax += __half2float(__low2half(a01));
        ay += __half2float(__high2half(a01));
        az += __half2float(__low2half(a23));
        aw += __half2float(__high2half(a23));
    }
    partial[idx] = make_float4(ax, ay, az, aw);
}

// Layer-1 reduce (sum 4 slice partials) + self-loop + fused MLP -> ps (half2).
__global__ __launch_bounds__(256) void l1_reduce_mlp(
    const float4* __restrict__ partial, const uint2* __restrict__ xs,
    const float* __restrict__ dinv,
    const float* __restrict__ W1, const float* __restrict__ b1,
    const float* __restrict__ W2, unsigned int* __restrict__ ps, int N) {
    __shared__ float sW1[256];
    __shared__ float sb1[64];
    __shared__ float sW2[128];
    int t = threadIdx.x;
    sW1[t] = W1[t];
    if (t < 64) sb1[t] = b1[t];
    if (t < 128) sW2[t] = W2[t];
    __syncthreads();
    int i = blockIdx.x * 256 + t;
    if (i >= N) return;
    int bucket = i >> BB, j = i & BMASK;
    float axs = 0.0f, ays = 0.0f, azs = 0.0f, aws = 0.0f;
    size_t kb = (size_t)bucket * SLICES;
    for (int s = 0; s < SLICES; ++s) {
        float4 v = partial[(kb + s) * BSZ + j];
        axs += v.x; ays += v.y; azs += v.z; aws += v.w;
    }
    float di = dinv[i];
    uint2 raw = xs[i];  // self-loop (quantized, consistent)
    __half2 h01 = u2h(raw.x), h23 = u2h(raw.y);
    float ax = (axs + __half2float(__low2half(h01))) * di;
    float ay = (ays + __half2float(__high2half(h01))) * di;
    float az = (azs + __half2float(__low2half(h23))) * di;
    float aw = (aws + __half2float(__high2half(h23))) * di;
    float p0 = 0.0f, p1 = 0.0f;
#pragma unroll
    for (int k = 0; k < 64; ++k) {
        float h = fmaf(ax, sW1[k],
                  fmaf(ay, sW1[64 + k],
                  fmaf(az, sW1[128 + k],
                  fmaf(aw, sW1[192 + k], sb1[k]))));
        h = fmaxf(h, 0.0f);
        p0 = fmaf(h, sW2[2 * k + 0], p0);
        p1 = fmaf(h, sW2[2 * k + 1], p1);
    }
    ps[i] = h2u(__halves2half2(__float2half_rn(p0 * di), __float2half_rn(p1 * di)));
}

// Layer-2 gather: same XCD-pinned mapping; ps slice (1 MB) is L2-resident.
__global__ __launch_bounds__(256) void l2_gather(
    const unsigned int* __restrict__ ebin2, const unsigned short* __restrict__ rp16,
    const unsigned int* __restrict__ gcur, const unsigned int* __restrict__ ps,
    float2* __restrict__ partial, unsigned int capk) {
    int bid = blockIdx.x, t = threadIdx.x;
    int r = bid & 7, s = r & 3, half = r >> 2, q = bid >> 3;
    int b = q >> 2, sub = (half << 2) | (q & 3);
    int key = (b << 2) | s;
    int idx = (key << BB) + (sub << 8) + t;
    unsigned int kb = (unsigned int)key * capk;
    unsigned int st = kb + rp16[idx];
    unsigned int en;
    if ((sub == 7) && (t == 255)) {
        unsigned int ner = gcur[key] - kb;
        en = kb + (ner < capk ? ner : capk);
    } else en = kb + rp16[idx + 1];
    float s0 = 0.0f, s1 = 0.0f;
    unsigned int e = st;
    for (; e + 2 <= en; e += 2) {
        unsigned int a = ebin2[e], bb = ebin2[e + 1];
        unsigned int ra = ps[a], rb2 = ps[bb];
        __half2 ha = u2h(ra), hb = u2h(rb2);
        s0 += __half2float(__low2half(ha)) + __half2float(__low2half(hb));
        s1 += __half2float(__high2half(ha)) + __half2float(__high2half(hb));
    }
    if (e < en) {
        __half2 h = u2h(ps[ebin2[e]]);
        s0 += __half2float(__low2half(h));
        s1 += __half2float(__high2half(h));
    }
    partial[idx] = make_float2(s0, s1);
}

// Layer-2 reduce + self-loop + bias -> out.
__global__ __launch_bounds__(256) void l2_reduce(
    const float2* __restrict__ partial, const unsigned int* __restrict__ ps,
    const float* __restrict__ dinv, const float* __restrict__ b2,
    float2* __restrict__ out, int N) {
    int i = blockIdx.x * 256 + threadIdx.x;
    if (i >= N) return;
    int bucket = i >> BB, j = i & BMASK;
    float s0 = 0.0f, s1 = 0.0f;
    size_t kb = (size_t)bucket * SLICES;
    for (int s = 0; s < SLICES; ++s) {
        float2 v = partial[(kb + s) * BSZ + j];
        s0 += v.x; s1 += v.y;
    }
    float di = dinv[i];
    __half2 h = u2h(ps[i]);  // self-loop
    float2 rr;
    rr.x = fmaf(s0 + __half2float(__low2half(h)), di, b2[0]);
    rr.y = fmaf(s1 + __half2float(__high2half(h)), di, b2[1]);
    out[i] = rr;
}

static inline size_t align256(size_t v) { return (v + 255) & ~(size_t)255; }

extern "C" void kernel_launch(void* const* d_in, const int* in_sizes, int n_in,
                              void* d_out, int out_size, void* d_ws, size_t ws_size,
                              hipStream_t stream) {
    const float* x  = (const float*)d_in[0];
    const int*   ei = (const int*)d_in[1];
    const float* W1 = (const float*)d_in[2];
    const float* b1 = (const float*)d_in[3];
    const float* W2 = (const float*)d_in[4];
    const float* b2 = (const float*)d_in[5];

    const int N = in_sizes[0] / 4;
    const int E = in_sizes[1] / 2;
    const int NB = (N + BSZ - 1) >> BB;
    const int NKEY = NB * SLICES;
    const int NBLKc = (E + CHUNK - 1) / CHUNK;

    // Static per-key capacity: mean + ~12.5% + 128, rounded to 64.
    unsigned int capk = (unsigned int)((E + NKEY - 1) / NKEY);
    capk = capk + capk / 8 + 128;
    capk = (capk + 63u) & ~63u;
    const unsigned int total_cap = (unsigned int)NKEY * capk;

    // Persistent buffers, then region R where partial ALIASES ebin
    // (ebin dead after sort2; partial written by l1_gather after).
    size_t o = 0;
    size_t o_cur  = o; o = align256(o + (size_t)NKEY * 4);                 // gcur
    size_t o_dinv = o; o = align256(o + (size_t)N * 4);                    // dinv
    size_t o_xs   = o; o = align256(o + (size_t)N * 8);                    // xs
    size_t o_ps   = o; o = align256(o + (size_t)N * 4);                    // ps
    size_t o_eb2  = o; o = align256(o + (size_t)total_cap * 4);            // ebin2 (padded)
    size_t o_rp   = o; o = align256(o + (size_t)NKEY * BSZ * 2);           // rp16
    size_t o_R    = o;                                                     // region R
    size_t o_ebin = o_R;                                                   // ebin (padded)

    char* ws = (char*)d_ws;
    unsigned int*   gcur  = (unsigned int*)(ws + o_cur);
    float*          dinv  = (float*)(ws + o_dinv);
    uint2*          xs    = (uint2*)(ws + o_xs);
    unsigned int*   ps    = (unsigned int*)(ws + o_ps);
    unsigned int*   ebin2 = (unsigned int*)(ws + o_eb2);
    unsigned short* rp16  = (unsigned short*)(ws + o_rp);
    unsigned int*   ebin  = (unsigned int*)(ws + o_ebin);
    float4*         part4 = (float4*)(ws + o_R);   // aliases ebin
    float2*         part2 = (float2*)(ws + o_R);   // sequential phases

    init_cur<<<(NKEY + 255) / 256, 256, 0, stream>>>(gcur, NKEY, capk);
    chunk_sort_flush<<<NBLKc, BTHREADS, 0, stream>>>(ei, E, NKEY, gcur, ebin, total_cap);
    sort2<<<NKEY, S2T, 0, stream>>>(ebin, gcur, ebin2, rp16, capk);
    deg_prep<<<(N + 255) / 256, 256, 0, stream>>>(rp16, gcur, (const float4*)x,
                                                  dinv, xs, N, capk);
    l1_gather<<<NB * 32, 256, 0, stream>>>(ebin2, rp16, gcur, xs, part4, capk);
    l1_reduce_mlp<<<(N + 255) / 256, 256, 0, stream>>>(part4, xs, dinv, W1, b1, W2, ps, N);
    l2_gather<<<NB * 32, 256, 0, stream>>>(ebin2, rp16, gcur, ps, part2, capk);
    l2_reduce<<<(N + 255) / 256, 256, 0, stream>>>(part2, ps, dinv, b2, (float2*)d_out, N);
}

// Round 9
// 298.514 us; speedup vs baseline: 1.2764x; 1.2764x over previous
//
#include <hip/hip_runtime.h>
#include <hip/hip_fp16.h>

#define CF_T 512         // chunk_sort_flush threads
#define EPT 31           // edges per thread (register-cached)
#define CHUNK (CF_T * EPT)   // 15872 edges per chunk (62 KB LDS staging)
#define BB 11            // bucket bits: 2048 nodes per bucket
#define BSZ (1 << BB)
#define BMASK (BSZ - 1)
#define SLICES 4         // src slices (xs slice = 2 MB -> per-XCD L2-resident)
#define SSHIFT 18        // src slice = src >> 18 (N <= 2^20)
#define MAXNKEY 2048     // max (bucket,slice) keys
#define S2T 512          // sort2 threads
#define SCAP 4608        // LDS staging cap per key (~mean 4090 + 8 sigma)
#define CP(i) ((i) + ((i) >> 5))   // +1-per-32 pad: breaks LDS bank conflicts

// ---------------- helpers ----------------
__device__ __forceinline__ int detect64(const int* __restrict__ ei) {
    return (ei[1] | ei[3] | ei[5] | ei[7] | ei[9] | ei[11] | ei[13] | ei[15]) == 0;
}
__device__ __forceinline__ int load_src(const int* __restrict__ ei, int e, int is64) {
    return is64 ? ei[2 * (size_t)e] : ei[(size_t)e];
}
__device__ __forceinline__ int load_dst(const int* __restrict__ ei, int E, int e, int is64) {
    return is64 ? ei[2 * ((size_t)E + e)] : ei[(size_t)E + e];
}
__device__ __forceinline__ unsigned int h2u(__half2 h) {
    union { __half2 h; unsigned int u; } c; c.h = h; return c.u;
}
__device__ __forceinline__ __half2 u2h(unsigned int u) {
    union { __half2 h; unsigned int u; } c; c.u = u; return c.h;
}

// Init per-key cursors to static region bases (no pre-histogram needed).
__global__ __launch_bounds__(256) void init_cur(
    unsigned int* __restrict__ gcur, int NKEY, unsigned int capk) {
    int k = blockIdx.x * 256 + threadIdx.x;
    if (k < NKEY) gcur[k] = (unsigned int)k * capk;
}

// chunk_sort_flush v2: one 15872-edge chunk, 13-bit (bucket,slice) LDS sort.
// Fixes vs r8: (a) edges register-cached during histogram (rec[31] + u16 keys)
// -> scatter phase has ZERO global loads; (b) runs are ~8 recs (CHUNK/NKEY),
// 2x r8 -> write amp ~1.9 not 2.5; (c) flush = 4 keys/wave x 16 lanes, no
// binary search; (d) 80 KB LDS exactly -> 2 blocks/CU; 505 blocks ~ 1 round.
__global__ __launch_bounds__(CF_T) void chunk_sort_flush(
    const int* __restrict__ ei, int E, int NKEY,
    unsigned int* __restrict__ gcur, unsigned int* __restrict__ ebin,
    unsigned int total_cap) {
    __shared__ unsigned int cnt[MAXNKEY];    // 8 KB: counts -> starts -> ends
    __shared__ unsigned int gdst[MAXNKEY];   // 8 KB: reserved_base - start (wrap ok)
    __shared__ unsigned int ssum[CF_T];      // 2 KB
    __shared__ unsigned int stg[CHUNK];      // 62 KB
    int t = threadIdx.x, blk = blockIdx.x;
    for (int u = t; u < MAXNKEY; u += CF_T) cnt[u] = 0;
    __syncthreads();
    int is64 = detect64(ei);
    int lo = blk * CHUNK;
    int hi = lo + CHUNK; if (hi > E) hi = E;
    // phase 1: load edges ONCE, cache rec + key in registers, histogram keys
    unsigned int rec[EPT];
    unsigned int ky[(EPT + 1) / 2];          // u16-packed keys, 16 VGPRs
#pragma unroll
    for (int j = 0; j < (EPT + 1) / 2; ++j) ky[j] = 0;
#pragma unroll
    for (int j = 0; j < EPT; ++j) {
        int e = lo + t + j * CF_T;
        if (e < hi) {
            int s = load_src(ei, e, is64);
            int d = load_dst(ei, E, e, is64);
            unsigned int key = ((unsigned int)(d >> BB) << 2) | (unsigned int)(s >> SSHIFT);
            rec[j] = ((unsigned int)s << BB) | (unsigned int)(d & BMASK);
            ky[j >> 1] |= key << ((j & 1) * 16);
            atomicAdd(&cnt[key], 1u);
        }
    }
    __syncthreads();
    // exclusive scan over 2048 counters: 4 contiguous per thread + block scan
    unsigned int v[4];
    unsigned int sum = 0;
#pragma unroll
    for (int j = 0; j < 4; ++j) { unsigned int c = cnt[4 * t + j]; v[j] = sum; sum += c; }
    ssum[t] = sum;
    __syncthreads();
    for (int o = 1; o < CF_T; o <<= 1) {
        unsigned int x2 = (t >= o) ? ssum[t - o] : 0;
        __syncthreads();
        ssum[t] += x2;
        __syncthreads();
    }
    unsigned int base = t ? ssum[t - 1] : 0;
#pragma unroll
    for (int j = 0; j < 4; ++j) cnt[4 * t + j] = base + v[j];
    __syncthreads();
    // phase 2: scatter from REGISTERS into LDS staging (no global loads)
#pragma unroll
    for (int j = 0; j < EPT; ++j) {
        int e = lo + t + j * CF_T;
        if (e < hi) {
            unsigned int key = (ky[j >> 1] >> ((j & 1) * 16)) & 0xFFFFu;
            unsigned int pos = atomicAdd(&cnt[key], 1u);
            stg[pos] = rec[j];
        }
    }
    __syncthreads();
    // reserve: post-scatter invariant cnt[u] == end(u); start(u) == (u?cnt[u-1]:0)
    for (int u = t; u < NKEY; u += CF_T) {
        unsigned int lst = u ? cnt[u - 1] : 0;
        unsigned int L = cnt[u] - lst;
        if (L) gdst[u] = atomicAdd(&gcur[u], L) - lst;
    }
    __syncthreads();
    // flush: 4 keys per wave, 16 lanes per key -> full-lane coalesced bursts
    int w = t >> 6, lane = t & 63, nw = CF_T >> 6;
    int g16 = lane >> 4, l16 = lane & 15;
    for (int u0 = w * 4; u0 < NKEY; u0 += nw * 4) {
        int u = u0 + g16;
        if (u < NKEY) {
            unsigned int lst = u ? cnt[u - 1] : 0;
            unsigned int en = cnt[u];
            for (unsigned int j = lst + l16; j < en; j += 16) {
                unsigned int gpos = gdst[u] + j;
                if (gpos < total_cap) ebin[gpos] = stg[j];
            }
        }
    }
}

// Per (bucket,slice) key: contiguous read of its padded ebin region, 11-bit
// counting sort by dstlow staged in LDS, coalesced flush to ebin2 (src ids),
// u16 row offsets rp16. 28 KB LDS -> balanced multi-block/CU.
__global__ __launch_bounds__(S2T) void sort2(
    const unsigned int* __restrict__ ebin, const unsigned int* __restrict__ gcur,
    unsigned int* __restrict__ ebin2, unsigned short* __restrict__ rp16,
    unsigned int capk) {
    __shared__ unsigned int cnt[CP(BSZ)];   // 8.4 KB, bank-padded
    __shared__ unsigned int ssum[S2T];      // 2 KB
    __shared__ unsigned int stg2[SCAP];     // 18 KB
    int k = blockIdx.x, t = threadIdx.x;
    for (int j = t; j < CP(BSZ); j += S2T) cnt[j] = 0;
    __syncthreads();
    unsigned int kb = (unsigned int)k * capk;
    unsigned int ne_raw = gcur[k] - kb;
    int ne = (int)(ne_raw < capk ? ne_raw : capk);
    // count phase: contiguous coalesced read
    for (int i = t; i < ne; i += S2T) {
        unsigned int k11 = ebin[kb + i] & BMASK;
        atomicAdd(&cnt[CP(k11)], 1u);
    }
    __syncthreads();
    // exclusive scan of 2048 counters: 4 contiguous per thread + block scan
    unsigned int loc[4];
    unsigned int s = 0;
#pragma unroll
    for (int j = 0; j < 4; ++j) { loc[j] = s; s += cnt[CP(4 * t + j)]; }
    ssum[t] = s;
    __syncthreads();
    for (int o = 1; o < S2T; o <<= 1) {
        unsigned int v = (t >= o) ? ssum[t - o] : 0;
        __syncthreads();
        ssum[t] += v;
        __syncthreads();
    }
    unsigned int tb = t ? ssum[t - 1] : 0;
    size_t rb = (size_t)k * BSZ;
#pragma unroll
    for (int j = 0; j < 4; ++j)
        rp16[rb + 4 * t + j] = (unsigned short)(tb + loc[j]);
#pragma unroll
    for (int j = 0; j < 4; ++j) cnt[CP(4 * t + j)] = tb + loc[j];
    __syncthreads();
    // scatter phase: re-read (L2-hot), scatter src ids into LDS staging
    for (int i = t; i < ne; i += S2T) {
        unsigned int rec = ebin[kb + i];
        unsigned int pos = atomicAdd(&cnt[CP(rec & BMASK)], 1u);
        unsigned int v = rec >> BB;   // src node id
        if (pos < SCAP) stg2[pos] = v;
        else ebin2[kb + pos] = v;     // overflow fallback (memory-safe, pos < capk)
    }
    __syncthreads();
    // coalesced flush to ebin2
    int m = ne < SCAP ? ne : SCAP;
    for (int j = t; j < m; j += S2T) ebin2[kb + j] = stg2[j];
}

// Node-parallel: degree from rp16 run-length differences (4 slices) -> dinv,
// xs = half4(x * dinv).
__global__ __launch_bounds__(256) void deg_prep(
    const unsigned short* __restrict__ rp16, const unsigned int* __restrict__ gcur,
    const float4* __restrict__ x, float* __restrict__ dinv, uint2* __restrict__ xs,
    int N, unsigned int capk) {
    int g = blockIdx.x * 256 + threadIdx.x;
    if (g >= N) return;
    int b = g >> BB, j = g & BMASK;
    unsigned int deg = 0;
#pragma unroll
    for (int s = 0; s < SLICES; ++s) {
        int key = (b << 2) | s;
        size_t rb = (size_t)key * BSZ;
        unsigned int st = rp16[rb + j];
        unsigned int en;
        if (j == BMASK) {
            unsigned int ner = gcur[key] - (unsigned int)key * capk;
            en = ner < capk ? ner : capk;
        } else en = rp16[rb + j + 1];
        deg += en - st;
    }
    float di = rsqrtf((float)(deg + 1u));
    dinv[g] = di;
    float4 v = x[g];
    uint2 p;
    p.x = h2u(__halves2half2(__float2half_rn(v.x * di), __float2half_rn(v.y * di)));
    p.y = h2u(__halves2half2(__float2half_rn(v.z * di), __float2half_rn(v.w * di)));
    xs[g] = p;
}

// Block remap: bid%8 determines XCD (round-robin dispatch); pin slice = (bid&3)
// so each XCD's gather working set is ONE 2 MB slice (round-2-proven mapping).
__global__ __launch_bounds__(256) void l1_gather(
    const unsigned int* __restrict__ ebin2, const unsigned short* __restrict__ rp16,
    const unsigned int* __restrict__ gcur, const uint2* __restrict__ xs,
    float4* __restrict__ partial, unsigned int capk) {
    int bid = blockIdx.x, t = threadIdx.x;
    int r = bid & 7, s = r & 3, half = r >> 2, q = bid >> 3;
    int b = q >> 2, sub = (half << 2) | (q & 3);
    int key = (b << 2) | s;
    int idx = (key << BB) + (sub << 8) + t;
    unsigned int kb = (unsigned int)key * capk;
    unsigned int st = kb + rp16[idx];
    unsigned int en;
    if ((sub == 7) && (t == 255)) {           // last node of this key's region
        unsigned int ner = gcur[key] - kb;
        en = kb + (ner < capk ? ner : capk);
    } else en = kb + rp16[idx + 1];
    float ax = 0.0f, ay = 0.0f, az = 0.0f, aw = 0.0f;
    unsigned int e = st;
    for (; e + 2 <= en; e += 2) {
        unsigned int s0 = ebin2[e], s1 = ebin2[e + 1];
        uint2 r0 = xs[s0], r1 = xs[s1];
        __half2 a01 = u2h(r0.x), a23 = u2h(r0.y);
        __half2 b01 = u2h(r1.x), b23 = u2h(r1.y);
        ax += __half2float(__low2half(a01)) + __half2float(__low2half(b01));
        ay += __half2float(__high2half(a01)) + __half2float(__high2half(b01));
        az += __half2float(__low2half(a23)) + __half2float(__low2half(b23));
        aw += __half2float(__high2half(a23)) + __half2float(__high2half(b23));
    }
    if (e < en) {
        uint2 rr = xs[ebin2[e]];
        __half2 a01 = u2h(rr.x), a23 = u2h(rr.y);
        ax += __half2float(__low2half(a01));
        ay += __half2float(__high2half(a01));
        az += __half2float(__low2half(a23));
        aw += __half2float(__high2half(a23));
    }
    partial[idx] = make_float4(ax, ay, az, aw);
}

// Layer-1 reduce (sum 4 slice partials) + self-loop + fused MLP -> ps (half2).
__global__ __launch_bounds__(256) void l1_reduce_mlp(
    const float4* __restrict__ partial, const uint2* __restrict__ xs,
    const float* __restrict__ dinv,
    const float* __restrict__ W1, const float* __restrict__ b1,
    const float* __restrict__ W2, unsigned int* __restrict__ ps, int N) {
    __shared__ float sW1[256];
    __shared__ float sb1[64];
    __shared__ float sW2[128];
    int t = threadIdx.x;
    sW1[t] = W1[t];
    if (t < 64) sb1[t] = b1[t];
    if (t < 128) sW2[t] = W2[t];
    __syncthreads();
    int i = blockIdx.x * 256 + t;
    if (i >= N) return;
    int bucket = i >> BB, j = i & BMASK;
    float axs = 0.0f, ays = 0.0f, azs = 0.0f, aws = 0.0f;
    size_t kb = (size_t)bucket * SLICES;
    for (int s = 0; s < SLICES; ++s) {
        float4 v = partial[(kb + s) * BSZ + j];
        axs += v.x; ays += v.y; azs += v.z; aws += v.w;
    }
    float di = dinv[i];
    uint2 raw = xs[i];  // self-loop (quantized, consistent)
    __half2 h01 = u2h(raw.x), h23 = u2h(raw.y);
    float ax = (axs + __half2float(__low2half(h01))) * di;
    float ay = (ays + __half2float(__high2half(h01))) * di;
    float az = (azs + __half2float(__low2half(h23))) * di;
    float aw = (aws + __half2float(__high2half(h23))) * di;
    float p0 = 0.0f, p1 = 0.0f;
#pragma unroll
    for (int k = 0; k < 64; ++k) {
        float h = fmaf(ax, sW1[k],
                  fmaf(ay, sW1[64 + k],
                  fmaf(az, sW1[128 + k],
                  fmaf(aw, sW1[192 + k], sb1[k]))));
        h = fmaxf(h, 0.0f);
        p0 = fmaf(h, sW2[2 * k + 0], p0);
        p1 = fmaf(h, sW2[2 * k + 1], p1);
    }
    ps[i] = h2u(__halves2half2(__float2half_rn(p0 * di), __float2half_rn(p1 * di)));
}

// Layer-2 gather: same XCD-pinned mapping; ps slice (1 MB) is L2-resident.
__global__ __launch_bounds__(256) void l2_gather(
    const unsigned int* __restrict__ ebin2, const unsigned short* __restrict__ rp16,
    const unsigned int* __restrict__ gcur, const unsigned int* __restrict__ ps,
    float2* __restrict__ partial, unsigned int capk) {
    int bid = blockIdx.x, t = threadIdx.x;
    int r = bid & 7, s = r & 3, half = r >> 2, q = bid >> 3;
    int b = q >> 2, sub = (half << 2) | (q & 3);
    int key = (b << 2) | s;
    int idx = (key << BB) + (sub << 8) + t;
    unsigned int kb = (unsigned int)key * capk;
    unsigned int st = kb + rp16[idx];
    unsigned int en;
    if ((sub == 7) && (t == 255)) {
        unsigned int ner = gcur[key] - kb;
        en = kb + (ner < capk ? ner : capk);
    } else en = kb + rp16[idx + 1];
    float s0 = 0.0f, s1 = 0.0f;
    unsigned int e = st;
    for (; e + 2 <= en; e += 2) {
        unsigned int a = ebin2[e], bb = ebin2[e + 1];
        unsigned int ra = ps[a], rb2 = ps[bb];
        __half2 ha = u2h(ra), hb = u2h(rb2);
        s0 += __half2float(__low2half(ha)) + __half2float(__low2half(hb));
        s1 += __half2float(__high2half(ha)) + __half2float(__high2half(hb));
    }
    if (e < en) {
        __half2 h = u2h(ps[ebin2[e]]);
        s0 += __half2float(__low2half(h));
        s1 += __half2float(__high2half(h));
    }
    partial[idx] = make_float2(s0, s1);
}

// Layer-2 reduce + self-loop + bias -> out.
__global__ __launch_bounds__(256) void l2_reduce(
    const float2* __restrict__ partial, const unsigned int* __restrict__ ps,
    const float* __restrict__ dinv, const float* __restrict__ b2,
    float2* __restrict__ out, int N) {
    int i = blockIdx.x * 256 + threadIdx.x;
    if (i >= N) return;
    int bucket = i >> BB, j = i & BMASK;
    float s0 = 0.0f, s1 = 0.0f;
    size_t kb = (size_t)bucket * SLICES;
    for (int s = 0; s < SLICES; ++s) {
        float2 v = partial[(kb + s) * BSZ + j];
        s0 += v.x; s1 += v.y;
    }
    float di = dinv[i];
    __half2 h = u2h(ps[i]);  // self-loop
    float2 rr;
    rr.x = fmaf(s0 + __half2float(__low2half(h)), di, b2[0]);
    rr.y = fmaf(s1 + __half2float(__high2half(h)), di, b2[1]);
    out[i] = rr;
}

static inline size_t align256(size_t v) { return (v + 255) & ~(size_t)255; }

extern "C" void kernel_launch(void* const* d_in, const int* in_sizes, int n_in,
                              void* d_out, int out_size, void* d_ws, size_t ws_size,
                              hipStream_t stream) {
    const float* x  = (const float*)d_in[0];
    const int*   ei = (const int*)d_in[1];
    const float* W1 = (const float*)d_in[2];
    const float* b1 = (const float*)d_in[3];
    const float* W2 = (const float*)d_in[4];
    const float* b2 = (const float*)d_in[5];

    const int N = in_sizes[0] / 4;
    const int E = in_sizes[1] / 2;
    const int NB = (N + BSZ - 1) >> BB;
    const int NKEY = NB * SLICES;
    const int NBLKc = (E + CHUNK - 1) / CHUNK;

    // Static per-key capacity: mean + ~12.5% + 128, rounded to 64.
    unsigned int capk = (unsigned int)((E + NKEY - 1) / NKEY);
    capk = capk + capk / 8 + 128;
    capk = (capk + 63u) & ~63u;
    const unsigned int total_cap = (unsigned int)NKEY * capk;

    // Persistent buffers, then region R where partial ALIASES ebin
    // (ebin dead after sort2; partial written by l1_gather after).
    size_t o = 0;
    size_t o_cur  = o; o = align256(o + (size_t)NKEY * 4);                 // gcur
    size_t o_dinv = o; o = align256(o + (size_t)N * 4);                    // dinv
    size_t o_xs   = o; o = align256(o + (size_t)N * 8);                    // xs
    size_t o_ps   = o; o = align256(o + (size_t)N * 4);                    // ps
    size_t o_eb2  = o; o = align256(o + (size_t)total_cap * 4);            // ebin2 (padded)
    size_t o_rp   = o; o = align256(o + (size_t)NKEY * BSZ * 2);           // rp16
    size_t o_R    = o;                                                     // region R
    size_t o_ebin = o_R;                                                   // ebin (padded)

    char* ws = (char*)d_ws;
    unsigned int*   gcur  = (unsigned int*)(ws + o_cur);
    float*          dinv  = (float*)(ws + o_dinv);
    uint2*          xs    = (uint2*)(ws + o_xs);
    unsigned int*   ps    = (unsigned int*)(ws + o_ps);
    unsigned int*   ebin2 = (unsigned int*)(ws + o_eb2);
    unsigned short* rp16  = (unsigned short*)(ws + o_rp);
    unsigned int*   ebin  = (unsigned int*)(ws + o_ebin);
    float4*         part4 = (float4*)(ws + o_R);   // aliases ebin
    float2*         part2 = (float2*)(ws + o_R);   // sequential phases

    init_cur<<<(NKEY + 255) / 256, 256, 0, stream>>>(gcur, NKEY, capk);
    chunk_sort_flush<<<NBLKc, CF_T, 0, stream>>>(ei, E, NKEY, gcur, ebin, total_cap);
    sort2<<<NKEY, S2T, 0, stream>>>(ebin, gcur, ebin2, rp16, capk);
    deg_prep<<<(N + 255) / 256, 256, 0, stream>>>(rp16, gcur, (const float4*)x,
                                                  dinv, xs, N, capk);
    l1_gather<<<NB * 32, 256, 0, stream>>>(ebin2, rp16, gcur, xs, part4, capk);
    l1_reduce_mlp<<<(N + 255) / 256, 256, 0, stream>>>(part4, xs, dinv, W1, b1, W2, ps, N);
    l2_gather<<<NB * 32, 256, 0, stream>>>(ebin2, rp16, gcur, ps, part2, capk);
    l2_reduce<<<(N + 255) / 256, 256, 0, stream>>>(part2, ps, dinv, b2, (float2*)d_out, N);
}

// Round 10
// 292.677 us; speedup vs baseline: 1.3019x; 1.0199x over previous
//
#include <hip/hip_runtime.h>
#include <hip/hip_fp16.h>

#define CF_T 512         // chunk_sort_flush threads
#define EPT 31           // edges per thread (register-cached)
#define CHUNK (CF_T * EPT)   // 15872 edges per chunk (62 KB LDS staging)
#define BB 11            // bucket bits: 2048 nodes per bucket
#define BSZ (1 << BB)
#define BMASK (BSZ - 1)
#define SLICES 4         // src slices (xs slice = 2 MB -> per-XCD L2-resident)
#define SSHIFT 18        // src slice = src >> 18 (N <= 2^20)
#define MAXNKEY 2048     // max (bucket,slice) keys
#define S2T 512          // sort2 threads
#define SCAP 4608        // LDS staging cap per key (~mean 4090 + 8 sigma)
#define CP(i) ((i) + ((i) >> 5))   // +1-per-32 pad: breaks LDS bank conflicts

// ---------------- helpers ----------------
__device__ __forceinline__ int detect64(const int* __restrict__ ei) {
    return (ei[1] | ei[3] | ei[5] | ei[7] | ei[9] | ei[11] | ei[13] | ei[15]) == 0;
}
__device__ __forceinline__ int load_src(const int* __restrict__ ei, int e, int is64) {
    return is64 ? ei[2 * (size_t)e] : ei[(size_t)e];
}
__device__ __forceinline__ int load_dst(const int* __restrict__ ei, int E, int e, int is64) {
    return is64 ? ei[2 * ((size_t)E + e)] : ei[(size_t)E + e];
}
__device__ __forceinline__ unsigned int h2u(__half2 h) {
    union { __half2 h; unsigned int u; } c; c.h = h; return c.u;
}
__device__ __forceinline__ __half2 u2h(unsigned int u) {
    union { __half2 h; unsigned int u; } c; c.u = u; return c.h;
}

// Init per-key cursors to static region bases (no pre-histogram needed).
__global__ __launch_bounds__(256) void init_cur(
    unsigned int* __restrict__ gcur, int NKEY, unsigned int capk) {
    int k = blockIdx.x * 256 + threadIdx.x;
    if (k < NKEY) gcur[k] = (unsigned int)k * capk;
}

// chunk_sort_flush (round-9 proven, 60 us): one 15872-edge chunk, 13-bit
// (bucket,slice) LDS sort, register-cached edges, reserve + group-of-16 flush.
__global__ __launch_bounds__(CF_T) void chunk_sort_flush(
    const int* __restrict__ ei, int E, int NKEY,
    unsigned int* __restrict__ gcur, unsigned int* __restrict__ ebin,
    unsigned int total_cap) {
    __shared__ unsigned int cnt[MAXNKEY];    // 8 KB: counts -> starts -> ends
    __shared__ unsigned int gdst[MAXNKEY];   // 8 KB: reserved_base - start (wrap ok)
    __shared__ unsigned int ssum[CF_T];      // 2 KB
    __shared__ unsigned int stg[CHUNK];      // 62 KB
    int t = threadIdx.x, blk = blockIdx.x;
    for (int u = t; u < MAXNKEY; u += CF_T) cnt[u] = 0;
    __syncthreads();
    int is64 = detect64(ei);
    int lo = blk * CHUNK;
    int hi = lo + CHUNK; if (hi > E) hi = E;
    // phase 1: load edges ONCE, cache rec + key in registers, histogram keys
    unsigned int rec[EPT];
    unsigned int ky[(EPT + 1) / 2];          // u16-packed keys, 16 VGPRs
#pragma unroll
    for (int j = 0; j < (EPT + 1) / 2; ++j) ky[j] = 0;
#pragma unroll
    for (int j = 0; j < EPT; ++j) {
        int e = lo + t + j * CF_T;
        if (e < hi) {
            int s = load_src(ei, e, is64);
            int d = load_dst(ei, E, e, is64);
            unsigned int key = ((unsigned int)(d >> BB) << 2) | (unsigned int)(s >> SSHIFT);
            rec[j] = ((unsigned int)s << BB) | (unsigned int)(d & BMASK);
            ky[j >> 1] |= key << ((j & 1) * 16);
            atomicAdd(&cnt[key], 1u);
        }
    }
    __syncthreads();
    // exclusive scan over 2048 counters: 4 contiguous per thread + block scan
    unsigned int v[4];
    unsigned int sum = 0;
#pragma unroll
    for (int j = 0; j < 4; ++j) { unsigned int c = cnt[4 * t + j]; v[j] = sum; sum += c; }
    ssum[t] = sum;
    __syncthreads();
    for (int o = 1; o < CF_T; o <<= 1) {
        unsigned int x2 = (t >= o) ? ssum[t - o] : 0;
        __syncthreads();
        ssum[t] += x2;
        __syncthreads();
    }
    unsigned int base = t ? ssum[t - 1] : 0;
#pragma unroll
    for (int j = 0; j < 4; ++j) cnt[4 * t + j] = base + v[j];
    __syncthreads();
    // phase 2: scatter from REGISTERS into LDS staging (no global loads)
#pragma unroll
    for (int j = 0; j < EPT; ++j) {
        int e = lo + t + j * CF_T;
        if (e < hi) {
            unsigned int key = (ky[j >> 1] >> ((j & 1) * 16)) & 0xFFFFu;
            unsigned int pos = atomicAdd(&cnt[key], 1u);
            stg[pos] = rec[j];
        }
    }
    __syncthreads();
    // reserve: post-scatter invariant cnt[u] == end(u); start(u) == (u?cnt[u-1]:0)
    for (int u = t; u < NKEY; u += CF_T) {
        unsigned int lst = u ? cnt[u - 1] : 0;
        unsigned int L = cnt[u] - lst;
        if (L) gdst[u] = atomicAdd(&gcur[u], L) - lst;
    }
    __syncthreads();
    // flush: 4 keys per wave, 16 lanes per key -> full-lane coalesced bursts
    int w = t >> 6, lane = t & 63, nw = CF_T >> 6;
    int g16 = lane >> 4, l16 = lane & 15;
    for (int u0 = w * 4; u0 < NKEY; u0 += nw * 4) {
        int u = u0 + g16;
        if (u < NKEY) {
            unsigned int lst = u ? cnt[u - 1] : 0;
            unsigned int en = cnt[u];
            for (unsigned int j = lst + l16; j < en; j += 16) {
                unsigned int gpos = gdst[u] + j;
                if (gpos < total_cap) ebin[gpos] = stg[j];
            }
        }
    }
}

// Per (bucket,slice) key: contiguous read of its padded ebin region, 11-bit
// counting sort by dstlow staged in LDS, coalesced flush to ebin2 (src ids),
// u16 row offsets rp16. 28 KB LDS -> balanced multi-block/CU.
__global__ __launch_bounds__(S2T) void sort2(
    const unsigned int* __restrict__ ebin, const unsigned int* __restrict__ gcur,
    unsigned int* __restrict__ ebin2, unsigned short* __restrict__ rp16,
    unsigned int capk) {
    __shared__ unsigned int cnt[CP(BSZ)];   // 8.4 KB, bank-padded
    __shared__ unsigned int ssum[S2T];      // 2 KB
    __shared__ unsigned int stg2[SCAP];     // 18 KB
    int k = blockIdx.x, t = threadIdx.x;
    for (int j = t; j < CP(BSZ); j += S2T) cnt[j] = 0;
    __syncthreads();
    unsigned int kb = (unsigned int)k * capk;
    unsigned int ne_raw = gcur[k] - kb;
    int ne = (int)(ne_raw < capk ? ne_raw : capk);
    // count phase: contiguous coalesced read
    for (int i = t; i < ne; i += S2T) {
        unsigned int k11 = ebin[kb + i] & BMASK;
        atomicAdd(&cnt[CP(k11)], 1u);
    }
    __syncthreads();
    // exclusive scan of 2048 counters: 4 contiguous per thread + block scan
    unsigned int loc[4];
    unsigned int s = 0;
#pragma unroll
    for (int j = 0; j < 4; ++j) { loc[j] = s; s += cnt[CP(4 * t + j)]; }
    ssum[t] = s;
    __syncthreads();
    for (int o = 1; o < S2T; o <<= 1) {
        unsigned int v = (t >= o) ? ssum[t - o] : 0;
        __syncthreads();
        ssum[t] += v;
        __syncthreads();
    }
    unsigned int tb = t ? ssum[t - 1] : 0;
    size_t rb = (size_t)k * BSZ;
#pragma unroll
    for (int j = 0; j < 4; ++j)
        rp16[rb + 4 * t + j] = (unsigned short)(tb + loc[j]);
#pragma unroll
    for (int j = 0; j < 4; ++j) cnt[CP(4 * t + j)] = tb + loc[j];
    __syncthreads();
    // scatter phase: re-read (L2-hot), scatter src ids into LDS staging
    for (int i = t; i < ne; i += S2T) {
        unsigned int rec = ebin[kb + i];
        unsigned int pos = atomicAdd(&cnt[CP(rec & BMASK)], 1u);
        unsigned int v = rec >> BB;   // src node id
        if (pos < SCAP) stg2[pos] = v;
        else ebin2[kb + pos] = v;     // overflow fallback (memory-safe, pos < capk)
    }
    __syncthreads();
    // coalesced flush to ebin2
    int m = ne < SCAP ? ne : SCAP;
    for (int j = t; j < m; j += S2T) ebin2[kb + j] = stg2[j];
}

// Node-parallel: degree from rp16 run-length differences (4 slices) -> dinv,
// xs = half4(x * dinv).
__global__ __launch_bounds__(256) void deg_prep(
    const unsigned short* __restrict__ rp16, const unsigned int* __restrict__ gcur,
    const float4* __restrict__ x, float* __restrict__ dinv, uint2* __restrict__ xs,
    int N, unsigned int capk) {
    int g = blockIdx.x * 256 + threadIdx.x;
    if (g >= N) return;
    int b = g >> BB, j = g & BMASK;
    unsigned int deg = 0;
#pragma unroll
    for (int s = 0; s < SLICES; ++s) {
        int key = (b << 2) | s;
        size_t rb = (size_t)key * BSZ;
        unsigned int st = rp16[rb + j];
        unsigned int en;
        if (j == BMASK) {
            unsigned int ner = gcur[key] - (unsigned int)key * capk;
            en = ner < capk ? ner : capk;
        } else en = rp16[rb + j + 1];
        deg += en - st;
    }
    float di = rsqrtf((float)(deg + 1u));
    dinv[g] = di;
    float4 v = x[g];
    uint2 p;
    p.x = h2u(__halves2half2(__float2half_rn(v.x * di), __float2half_rn(v.y * di)));
    p.y = h2u(__halves2half2(__float2half_rn(v.z * di), __float2half_rn(v.w * di)));
    xs[g] = p;
}

// Layer-1 FUSED: thread = node; accumulate all 4 slice runs in REGISTERS
// (no partial buffer, no reduce kernel), then self-loop + MLP inline -> ps.
// Phase rotation: block's XCD proxy (bid&7) offsets the slice order so each
// XCD's concurrent gathers stay within ~one 2 MB xs slice (L2-resident).
__global__ __launch_bounds__(256) void l1_fused(
    const unsigned int* __restrict__ ebin2, const unsigned short* __restrict__ rp16,
    const unsigned int* __restrict__ gcur, const uint2* __restrict__ xs,
    const float* __restrict__ dinv,
    const float* __restrict__ W1, const float* __restrict__ b1,
    const float* __restrict__ W2, unsigned int* __restrict__ ps,
    int N, unsigned int capk) {
    __shared__ float sW1[256];
    __shared__ float sb1[64];
    __shared__ float sW2[128];
    int t = threadIdx.x, bid = blockIdx.x;
    sW1[t] = W1[t];
    if (t < 64) sb1[t] = b1[t];
    if (t < 128) sW2[t] = W2[t];
    __syncthreads();
    int g = bid * 256 + t;
    if (g >= N) return;
    int b = g >> BB, j = g & BMASK;
    int xcd = bid & 7;
    float axs = 0.0f, ays = 0.0f, azs = 0.0f, aws = 0.0f;
#pragma unroll
    for (int p = 0; p < SLICES; ++p) {
        int s = (xcd + p) & 3;
        int key = (b << 2) | s;
        unsigned int kb = (unsigned int)key * capk;
        size_t rb = (size_t)key * BSZ;
        unsigned int st = kb + rp16[rb + j];
        unsigned int en;
        if (j == BMASK) {
            unsigned int ner = gcur[key] - kb;
            en = kb + (ner < capk ? ner : capk);
        } else en = kb + rp16[rb + j + 1];
        unsigned int e = st;
        for (; e + 2 <= en; e += 2) {
            unsigned int s0 = ebin2[e], s1 = ebin2[e + 1];
            uint2 r0 = xs[s0], r1 = xs[s1];
            __half2 a01 = u2h(r0.x), a23 = u2h(r0.y);
            __half2 b01 = u2h(r1.x), b23 = u2h(r1.y);
            axs += __half2float(__low2half(a01)) + __half2float(__low2half(b01));
            ays += __half2float(__high2half(a01)) + __half2float(__high2half(b01));
            azs += __half2float(__low2half(a23)) + __half2float(__low2half(b23));
            aws += __half2float(__high2half(a23)) + __half2float(__high2half(b23));
        }
        if (e < en) {
            uint2 rr = xs[ebin2[e]];
            __half2 a01 = u2h(rr.x), a23 = u2h(rr.y);
            axs += __half2float(__low2half(a01));
            ays += __half2float(__high2half(a01));
            azs += __half2float(__low2half(a23));
            aws += __half2float(__high2half(a23));
        }
    }
    float di = dinv[g];
    uint2 raw = xs[g];  // self-loop (quantized, consistent)
    __half2 h01 = u2h(raw.x), h23 = u2h(raw.y);
    float ax = (axs + __half2float(__low2half(h01))) * di;
    float ay = (ays + __half2float(__high2half(h01))) * di;
    float az = (azs + __half2float(__low2half(h23))) * di;
    float aw = (aws + __half2float(__high2half(h23))) * di;
    float p0 = 0.0f, p1 = 0.0f;
#pragma unroll
    for (int k = 0; k < 64; ++k) {
        float h = fmaf(ax, sW1[k],
                  fmaf(ay, sW1[64 + k],
                  fmaf(az, sW1[128 + k],
                  fmaf(aw, sW1[192 + k], sb1[k]))));
        h = fmaxf(h, 0.0f);
        p0 = fmaf(h, sW2[2 * k + 0], p0);
        p1 = fmaf(h, sW2[2 * k + 1], p1);
    }
    ps[g] = h2u(__halves2half2(__float2half_rn(p0 * di), __float2half_rn(p1 * di)));
}

// Layer-2 FUSED: same structure, gathers ps (1 MB slices), epilogue writes out.
__global__ __launch_bounds__(256) void l2_fused(
    const unsigned int* __restrict__ ebin2, const unsigned short* __restrict__ rp16,
    const unsigned int* __restrict__ gcur, const unsigned int* __restrict__ ps,
    const float* __restrict__ dinv, const float* __restrict__ b2,
    float2* __restrict__ out, int N, unsigned int capk) {
    int t = threadIdx.x, bid = blockIdx.x;
    int g = bid * 256 + t;
    if (g >= N) return;
    int b = g >> BB, j = g & BMASK;
    int xcd = bid & 7;
    float s0 = 0.0f, s1 = 0.0f;
#pragma unroll
    for (int p = 0; p < SLICES; ++p) {
        int s = (xcd + p) & 3;
        int key = (b << 2) | s;
        unsigned int kb = (unsigned int)key * capk;
        size_t rb = (size_t)key * BSZ;
        unsigned int st = kb + rp16[rb + j];
        unsigned int en;
        if (j == BMASK) {
            unsigned int ner = gcur[key] - kb;
            en = kb + (ner < capk ? ner : capk);
        } else en = kb + rp16[rb + j + 1];
        unsigned int e = st;
        for (; e + 2 <= en; e += 2) {
            unsigned int a = ebin2[e], bb = ebin2[e + 1];
            unsigned int ra = ps[a], rb2 = ps[bb];
            __half2 ha = u2h(ra), hb = u2h(rb2);
            s0 += __half2float(__low2half(ha)) + __half2float(__low2half(hb));
            s1 += __half2float(__high2half(ha)) + __half2float(__high2half(hb));
        }
        if (e < en) {
            __half2 h = u2h(ps[ebin2[e]]);
            s0 += __half2float(__low2half(h));
            s1 += __half2float(__high2half(h));
        }
    }
    float di = dinv[g];
    __half2 h = u2h(ps[g]);  // self-loop
    float2 rr;
    rr.x = fmaf(s0 + __half2float(__low2half(h)), di, b2[0]);
    rr.y = fmaf(s1 + __half2float(__high2half(h)), di, b2[1]);
    out[g] = rr;
}

static inline size_t align256(size_t v) { return (v + 255) & ~(size_t)255; }

extern "C" void kernel_launch(void* const* d_in, const int* in_sizes, int n_in,
                              void* d_out, int out_size, void* d_ws, size_t ws_size,
                              hipStream_t stream) {
    const float* x  = (const float*)d_in[0];
    const int*   ei = (const int*)d_in[1];
    const float* W1 = (const float*)d_in[2];
    const float* b1 = (const float*)d_in[3];
    const float* W2 = (const float*)d_in[4];
    const float* b2 = (const float*)d_in[5];

    const int N = in_sizes[0] / 4;
    const int E = in_sizes[1] / 2;
    const int NB = (N + BSZ - 1) >> BB;
    const int NKEY = NB * SLICES;
    const int NBLKc = (E + CHUNK - 1) / CHUNK;
    const int NBLKn = (N + 255) / 256;

    // Static per-key capacity: mean + ~12.5% + 128, rounded to 64.
    unsigned int capk = (unsigned int)((E + NKEY - 1) / NKEY);
    capk = capk + capk / 8 + 128;
    capk = (capk + 63u) & ~63u;
    const unsigned int total_cap = (unsigned int)NKEY * capk;

    size_t o = 0;
    size_t o_cur  = o; o = align256(o + (size_t)NKEY * 4);                 // gcur
    size_t o_dinv = o; o = align256(o + (size_t)N * 4);                    // dinv
    size_t o_xs   = o; o = align256(o + (size_t)N * 8);                    // xs
    size_t o_ps   = o; o = align256(o + (size_t)N * 4);                    // ps
    size_t o_eb2  = o; o = align256(o + (size_t)total_cap * 4);            // ebin2 (padded)
    size_t o_rp   = o; o = align256(o + (size_t)NKEY * BSZ * 2);           // rp16
    size_t o_ebin = o; o = align256(o + (size_t)total_cap * 4);            // ebin (padded)

    char* ws = (char*)d_ws;
    unsigned int*   gcur  = (unsigned int*)(ws + o_cur);
    float*          dinv  = (float*)(ws + o_dinv);
    uint2*          xs    = (uint2*)(ws + o_xs);
    unsigned int*   ps    = (unsigned int*)(ws + o_ps);
    unsigned int*   ebin2 = (unsigned int*)(ws + o_eb2);
    unsigned short* rp16  = (unsigned short*)(ws + o_rp);
    unsigned int*   ebin  = (unsigned int*)(ws + o_ebin);

    init_cur<<<(NKEY + 255) / 256, 256, 0, stream>>>(gcur, NKEY, capk);
    chunk_sort_flush<<<NBLKc, CF_T, 0, stream>>>(ei, E, NKEY, gcur, ebin, total_cap);
    sort2<<<NKEY, S2T, 0, stream>>>(ebin, gcur, ebin2, rp16, capk);
    deg_prep<<<NBLKn, 256, 0, stream>>>(rp16, gcur, (const float4*)x, dinv, xs, N, capk);
    l1_fused<<<NBLKn, 256, 0, stream>>>(ebin2, rp16, gcur, xs, dinv, W1, b1, W2, ps, N, capk);
    l2_fused<<<NBLKn, 256, 0, stream>>>(ebin2, rp16, gcur, ps, dinv, b2, (float2*)d_out, N, capk);
}

// Round 11
// 291.518 us; speedup vs baseline: 1.3071x; 1.0040x over previous
//
#include <hip/hip_runtime.h>
#include <hip/hip_fp16.h>

#define CF_T 512         // chunk_sort_flush threads
#define EPT 31           // edges per thread (register-cached)
#define CHUNK (CF_T * EPT)   // 15872 edges per chunk (62 KB LDS staging)
#define BB 11            // bucket bits: 2048 nodes per bucket
#define BSZ (1 << BB)
#define BMASK (BSZ - 1)
#define SLICES 4         // src slices (xs slice = 2 MB -> per-XCD L2-resident)
#define SSHIFT 18        // src slice = src >> 18 (N <= 2^20)
#define MAXNKEY 2048     // max (bucket,slice) keys
#define S2T 512          // sort2 threads
#define SCAP 4608        // LDS staging cap per key (~mean 4090 + 8 sigma)
#define CP(i) ((i) + ((i) >> 5))   // +1-per-32 pad: breaks LDS bank conflicts

// ---------------- helpers ----------------
__device__ __forceinline__ int detect64(const int* __restrict__ ei) {
    return (ei[1] | ei[3] | ei[5] | ei[7] | ei[9] | ei[11] | ei[13] | ei[15]) == 0;
}
__device__ __forceinline__ int load_src(const int* __restrict__ ei, int e, int is64) {
    return is64 ? ei[2 * (size_t)e] : ei[(size_t)e];
}
__device__ __forceinline__ int load_dst(const int* __restrict__ ei, int E, int e, int is64) {
    return is64 ? ei[2 * ((size_t)E + e)] : ei[(size_t)E + e];
}
__device__ __forceinline__ unsigned int h2u(__half2 h) {
    union { __half2 h; unsigned int u; } c; c.h = h; return c.u;
}
__device__ __forceinline__ __half2 u2h(unsigned int u) {
    union { __half2 h; unsigned int u; } c; c.u = u; return c.h;
}

// Init per-key cursors to static region bases (no pre-histogram needed).
__global__ __launch_bounds__(256) void init_cur(
    unsigned int* __restrict__ gcur, int NKEY, unsigned int capk) {
    int k = blockIdx.x * 256 + threadIdx.x;
    if (k < NKEY) gcur[k] = (unsigned int)k * capk;
}

// chunk_sort_flush v3: round-9 structure + XCD-CONTIGUOUS chunk assignment.
// chunk = (bid%8)*CPX + bid/8: with round-robin bid->XCD dispatch, XCD x owns
// chunks [x*CPX,(x+1)*CPX), so all appends to a key region from one XCD are
// ADJACENT -> key-region tail lines fill entirely within one L2 (no cross-XCD
// ping-pong mid-line). Expected write amp 1.8 -> ~1.06.
__global__ __launch_bounds__(CF_T) void chunk_sort_flush(
    const int* __restrict__ ei, int E, int NKEY, int CPX,
    unsigned int* __restrict__ gcur, unsigned int* __restrict__ ebin,
    unsigned int total_cap) {
    __shared__ unsigned int cnt[MAXNKEY];    // 8 KB: counts -> starts -> ends
    __shared__ unsigned int gdst[MAXNKEY];   // 8 KB: reserved_base - start (wrap ok)
    __shared__ unsigned int ssum[CF_T];      // 2 KB
    __shared__ unsigned int stg[CHUNK];      // 62 KB
    int t = threadIdx.x, bid = blockIdx.x;
    int blk = (bid & 7) * CPX + (bid >> 3);  // XCD-contiguous chunk id
    int lo = blk * CHUNK;
    if (lo >= E) return;                     // block-uniform early exit (pre-barrier)
    int hi = lo + CHUNK; if (hi > E) hi = E;
    for (int u = t; u < MAXNKEY; u += CF_T) cnt[u] = 0;
    __syncthreads();
    int is64 = detect64(ei);
    // phase 1: load edges ONCE, cache rec + key in registers, histogram keys
    unsigned int rec[EPT];
    unsigned int ky[(EPT + 1) / 2];          // u16-packed keys, 16 VGPRs
#pragma unroll
    for (int j = 0; j < (EPT + 1) / 2; ++j) ky[j] = 0;
#pragma unroll
    for (int j = 0; j < EPT; ++j) {
        int e = lo + t + j * CF_T;
        if (e < hi) {
            int s = load_src(ei, e, is64);
            int d = load_dst(ei, E, e, is64);
            unsigned int key = ((unsigned int)(d >> BB) << 2) | (unsigned int)(s >> SSHIFT);
            rec[j] = ((unsigned int)s << BB) | (unsigned int)(d & BMASK);
            ky[j >> 1] |= key << ((j & 1) * 16);
            atomicAdd(&cnt[key], 1u);
        }
    }
    __syncthreads();
    // exclusive scan over 2048 counters: 4 contiguous per thread + block scan
    unsigned int v[4];
    unsigned int sum = 0;
#pragma unroll
    for (int j = 0; j < 4; ++j) { unsigned int c = cnt[4 * t + j]; v[j] = sum; sum += c; }
    ssum[t] = sum;
    __syncthreads();
    for (int o = 1; o < CF_T; o <<= 1) {
        unsigned int x2 = (t >= o) ? ssum[t - o] : 0;
        __syncthreads();
        ssum[t] += x2;
        __syncthreads();
    }
    unsigned int base = t ? ssum[t - 1] : 0;
#pragma unroll
    for (int j = 0; j < 4; ++j) cnt[4 * t + j] = base + v[j];
    __syncthreads();
    // phase 2: scatter from REGISTERS into LDS staging (no global loads)
#pragma unroll
    for (int j = 0; j < EPT; ++j) {
        int e = lo + t + j * CF_T;
        if (e < hi) {
            unsigned int key = (ky[j >> 1] >> ((j & 1) * 16)) & 0xFFFFu;
            unsigned int pos = atomicAdd(&cnt[key], 1u);
            stg[pos] = rec[j];
        }
    }
    __syncthreads();
    // reserve: post-scatter invariant cnt[u] == end(u); start(u) == (u?cnt[u-1]:0)
    for (int u = t; u < NKEY; u += CF_T) {
        unsigned int lst = u ? cnt[u - 1] : 0;
        unsigned int L = cnt[u] - lst;
        if (L) gdst[u] = atomicAdd(&gcur[u], L) - lst;
    }
    __syncthreads();
    // flush: 4 keys per wave, 16 lanes per key -> full-lane coalesced bursts
    int w = t >> 6, lane = t & 63, nw = CF_T >> 6;
    int g16 = lane >> 4, l16 = lane & 15;
    for (int u0 = w * 4; u0 < NKEY; u0 += nw * 4) {
        int u = u0 + g16;
        if (u < NKEY) {
            unsigned int lst = u ? cnt[u - 1] : 0;
            unsigned int en = cnt[u];
            for (unsigned int j = lst + l16; j < en; j += 16) {
                unsigned int gpos = gdst[u] + j;
                if (gpos < total_cap) ebin[gpos] = stg[j];
            }
        }
    }
}

// Per (bucket,slice) key: contiguous read of its padded ebin region, 11-bit
// counting sort by dstlow staged in LDS, coalesced flush to ebin2 (src ids),
// u16 row offsets rp16. 28 KB LDS -> balanced multi-block/CU.
__global__ __launch_bounds__(S2T) void sort2(
    const unsigned int* __restrict__ ebin, const unsigned int* __restrict__ gcur,
    unsigned int* __restrict__ ebin2, unsigned short* __restrict__ rp16,
    unsigned int capk) {
    __shared__ unsigned int cnt[CP(BSZ)];   // 8.4 KB, bank-padded
    __shared__ unsigned int ssum[S2T];      // 2 KB
    __shared__ unsigned int stg2[SCAP];     // 18 KB
    int k = blockIdx.x, t = threadIdx.x;
    for (int j = t; j < CP(BSZ); j += S2T) cnt[j] = 0;
    __syncthreads();
    unsigned int kb = (unsigned int)k * capk;
    unsigned int ne_raw = gcur[k] - kb;
    int ne = (int)(ne_raw < capk ? ne_raw : capk);
    // count phase: contiguous coalesced read
    for (int i = t; i < ne; i += S2T) {
        unsigned int k11 = ebin[kb + i] & BMASK;
        atomicAdd(&cnt[CP(k11)], 1u);
    }
    __syncthreads();
    // exclusive scan of 2048 counters: 4 contiguous per thread + block scan
    unsigned int loc[4];
    unsigned int s = 0;
#pragma unroll
    for (int j = 0; j < 4; ++j) { loc[j] = s; s += cnt[CP(4 * t + j)]; }
    ssum[t] = s;
    __syncthreads();
    for (int o = 1; o < S2T; o <<= 1) {
        unsigned int v = (t >= o) ? ssum[t - o] : 0;
        __syncthreads();
        ssum[t] += v;
        __syncthreads();
    }
    unsigned int tb = t ? ssum[t - 1] : 0;
    size_t rb = (size_t)k * BSZ;
#pragma unroll
    for (int j = 0; j < 4; ++j)
        rp16[rb + 4 * t + j] = (unsigned short)(tb + loc[j]);
#pragma unroll
    for (int j = 0; j < 4; ++j) cnt[CP(4 * t + j)] = tb + loc[j];
    __syncthreads();
    // scatter phase: re-read (L2-hot), scatter src ids into LDS staging
    for (int i = t; i < ne; i += S2T) {
        unsigned int rec = ebin[kb + i];
        unsigned int pos = atomicAdd(&cnt[CP(rec & BMASK)], 1u);
        unsigned int v = rec >> BB;   // src node id
        if (pos < SCAP) stg2[pos] = v;
        else ebin2[kb + pos] = v;     // overflow fallback (memory-safe, pos < capk)
    }
    __syncthreads();
    // coalesced flush to ebin2
    int m = ne < SCAP ? ne : SCAP;
    for (int j = t; j < m; j += S2T) ebin2[kb + j] = stg2[j];
}

// Node-parallel: degree from rp16 run-length differences (4 slices) -> dinv,
// xs = half4(x * dinv).
__global__ __launch_bounds__(256) void deg_prep(
    const unsigned short* __restrict__ rp16, const unsigned int* __restrict__ gcur,
    const float4* __restrict__ x, float* __restrict__ dinv, uint2* __restrict__ xs,
    int N, unsigned int capk) {
    int g = blockIdx.x * 256 + threadIdx.x;
    if (g >= N) return;
    int b = g >> BB, j = g & BMASK;
    unsigned int deg = 0;
#pragma unroll
    for (int s = 0; s < SLICES; ++s) {
        int key = (b << 2) | s;
        size_t rb = (size_t)key * BSZ;
        unsigned int st = rp16[rb + j];
        unsigned int en;
        if (j == BMASK) {
            unsigned int ner = gcur[key] - (unsigned int)key * capk;
            en = ner < capk ? ner : capk;
        } else en = rp16[rb + j + 1];
        deg += en - st;
    }
    float di = rsqrtf((float)(deg + 1u));
    dinv[g] = di;
    float4 v = x[g];
    uint2 p;
    p.x = h2u(__halves2half2(__float2half_rn(v.x * di), __float2half_rn(v.y * di)));
    p.y = h2u(__halves2half2(__float2half_rn(v.z * di), __float2half_rn(v.w * di)));
    xs[g] = p;
}

// Layer-1 FUSED: thread = node; accumulate all 4 slice runs in REGISTERS
// (no partial buffer, no reduce kernel), then self-loop + MLP inline -> ps.
// Phase rotation: block's XCD proxy (bid&7) offsets the slice order so each
// XCD's concurrent gathers stay within ~one 2 MB xs slice (L2-resident).
__global__ __launch_bounds__(256) void l1_fused(
    const unsigned int* __restrict__ ebin2, const unsigned short* __restrict__ rp16,
    const unsigned int* __restrict__ gcur, const uint2* __restrict__ xs,
    const float* __restrict__ dinv,
    const float* __restrict__ W1, const float* __restrict__ b1,
    const float* __restrict__ W2, unsigned int* __restrict__ ps,
    int N, unsigned int capk) {
    __shared__ float sW1[256];
    __shared__ float sb1[64];
    __shared__ float sW2[128];
    int t = threadIdx.x, bid = blockIdx.x;
    sW1[t] = W1[t];
    if (t < 64) sb1[t] = b1[t];
    if (t < 128) sW2[t] = W2[t];
    __syncthreads();
    int g = bid * 256 + t;
    if (g >= N) return;
    int b = g >> BB, j = g & BMASK;
    int xcd = bid & 7;
    float axs = 0.0f, ays = 0.0f, azs = 0.0f, aws = 0.0f;
#pragma unroll
    for (int p = 0; p < SLICES; ++p) {
        int s = (xcd + p) & 3;
        int key = (b << 2) | s;
        unsigned int kb = (unsigned int)key * capk;
        size_t rb = (size_t)key * BSZ;
        unsigned int st = kb + rp16[rb + j];
        unsigned int en;
        if (j == BMASK) {
            unsigned int ner = gcur[key] - kb;
            en = kb + (ner < capk ? ner : capk);
        } else en = kb + rp16[rb + j + 1];
        unsigned int e = st;
        for (; e + 2 <= en; e += 2) {
            unsigned int s0 = ebin2[e], s1 = ebin2[e + 1];
            uint2 r0 = xs[s0], r1 = xs[s1];
            __half2 a01 = u2h(r0.x), a23 = u2h(r0.y);
            __half2 b01 = u2h(r1.x), b23 = u2h(r1.y);
            axs += __half2float(__low2half(a01)) + __half2float(__low2half(b01));
            ays += __half2float(__high2half(a01)) + __half2float(__high2half(b01));
            azs += __half2float(__low2half(a23)) + __half2float(__low2half(b23));
            aws += __half2float(__high2half(a23)) + __half2float(__high2half(b23));
        }
        if (e < en) {
            uint2 rr = xs[ebin2[e]];
            __half2 a01 = u2h(rr.x), a23 = u2h(rr.y);
            axs += __half2float(__low2half(a01));
            ays += __half2float(__high2half(a01));
            azs += __half2float(__low2half(a23));
            aws += __half2float(__high2half(a23));
        }
    }
    float di = dinv[g];
    uint2 raw = xs[g];  // self-loop (quantized, consistent)
    __half2 h01 = u2h(raw.x), h23 = u2h(raw.y);
    float ax = (axs + __half2float(__low2half(h01))) * di;
    float ay = (ays + __half2float(__high2half(h01))) * di;
    float az = (azs + __half2float(__low2half(h23))) * di;
    float aw = (aws + __half2float(__high2half(h23))) * di;
    float p0 = 0.0f, p1 = 0.0f;
#pragma unroll
    for (int k = 0; k < 64; ++k) {
        float h = fmaf(ax, sW1[k],
                  fmaf(ay, sW1[64 + k],
                  fmaf(az, sW1[128 + k],
                  fmaf(aw, sW1[192 + k], sb1[k]))));
        h = fmaxf(h, 0.0f);
        p0 = fmaf(h, sW2[2 * k + 0], p0);
        p1 = fmaf(h, sW2[2 * k + 1], p1);
    }
    ps[g] = h2u(__halves2half2(__float2half_rn(p0 * di), __float2half_rn(p1 * di)));
}

// Layer-2 FUSED: same structure, gathers ps (1 MB slices), epilogue writes out.
__global__ __launch_bounds__(256) void l2_fused(
    const unsigned int* __restrict__ ebin2, const unsigned short* __restrict__ rp16,
    const unsigned int* __restrict__ gcur, const unsigned int* __restrict__ ps,
    const float* __restrict__ dinv, const float* __restrict__ b2,
    float2* __restrict__ out, int N, unsigned int capk) {
    int t = threadIdx.x, bid = blockIdx.x;
    int g = bid * 256 + t;
    if (g >= N) return;
    int b = g >> BB, j = g & BMASK;
    int xcd = bid & 7;
    float s0 = 0.0f, s1 = 0.0f;
#pragma unroll
    for (int p = 0; p < SLICES; ++p) {
        int s = (xcd + p) & 3;
        int key = (b << 2) | s;
        unsigned int kb = (unsigned int)key * capk;
        size_t rb = (size_t)key * BSZ;
        unsigned int st = kb + rp16[rb + j];
        unsigned int en;
        if (j == BMASK) {
            unsigned int ner = gcur[key] - kb;
            en = kb + (ner < capk ? ner : capk);
        } else en = kb + rp16[rb + j + 1];
        unsigned int e = st;
        for (; e + 2 <= en; e += 2) {
            unsigned int a = ebin2[e], bb = ebin2[e + 1];
            unsigned int ra = ps[a], rb2 = ps[bb];
            __half2 ha = u2h(ra), hb = u2h(rb2);
            s0 += __half2float(__low2half(ha)) + __half2float(__low2half(hb));
            s1 += __half2float(__high2half(ha)) + __half2float(__high2half(hb));
        }
        if (e < en) {
            __half2 h = u2h(ps[ebin2[e]]);
            s0 += __half2float(__low2half(h));
            s1 += __half2float(__high2half(h));
        }
    }
    float di = dinv[g];
    __half2 h = u2h(ps[g]);  // self-loop
    float2 rr;
    rr.x = fmaf(s0 + __half2float(__low2half(h)), di, b2[0]);
    rr.y = fmaf(s1 + __half2float(__high2half(h)), di, b2[1]);
    out[g] = rr;
}

static inline size_t align256(size_t v) { return (v + 255) & ~(size_t)255; }

extern "C" void kernel_launch(void* const* d_in, const int* in_sizes, int n_in,
                              void* d_out, int out_size, void* d_ws, size_t ws_size,
                              hipStream_t stream) {
    const float* x  = (const float*)d_in[0];
    const int*   ei = (const int*)d_in[1];
    const float* W1 = (const float*)d_in[2];
    const float* b1 = (const float*)d_in[3];
    const float* W2 = (const float*)d_in[4];
    const float* b2 = (const float*)d_in[5];

    const int N = in_sizes[0] / 4;
    const int E = in_sizes[1] / 2;
    const int NB = (N + BSZ - 1) >> BB;
    const int NKEY = NB * SLICES;
    const int NBLKc = (E + CHUNK - 1) / CHUNK;
    const int CPX = (NBLKc + 7) / 8;       // chunks per XCD
    const int NBLKn = (N + 255) / 256;

    // Static per-key capacity: mean + ~12.5% + 128, rounded to 64.
    unsigned int capk = (unsigned int)((E + NKEY - 1) / NKEY);
    capk = capk + capk / 8 + 128;
    capk = (capk + 63u) & ~63u;
    const unsigned int total_cap = (unsigned int)NKEY * capk;

    size_t o = 0;
    size_t o_cur  = o; o = align256(o + (size_t)NKEY * 4);                 // gcur
    size_t o_dinv = o; o = align256(o + (size_t)N * 4);                    // dinv
    size_t o_xs   = o; o = align256(o + (size_t)N * 8);                    // xs
    size_t o_ps   = o; o = align256(o + (size_t)N * 4);                    // ps
    size_t o_eb2  = o; o = align256(o + (size_t)total_cap * 4);            // ebin2 (padded)
    size_t o_rp   = o; o = align256(o + (size_t)NKEY * BSZ * 2);           // rp16
    size_t o_ebin = o; o = align256(o + (size_t)total_cap * 4);            // ebin (padded)

    char* ws = (char*)d_ws;
    unsigned int*   gcur  = (unsigned int*)(ws + o_cur);
    float*          dinv  = (float*)(ws + o_dinv);
    uint2*          xs    = (uint2*)(ws + o_xs);
    unsigned int*   ps    = (unsigned int*)(ws + o_ps);
    unsigned int*   ebin2 = (unsigned int*)(ws + o_eb2);
    unsigned short* rp16  = (unsigned short*)(ws + o_rp);
    unsigned int*   ebin  = (unsigned int*)(ws + o_ebin);

    init_cur<<<(NKEY + 255) / 256, 256, 0, stream>>>(gcur, NKEY, capk);
    chunk_sort_flush<<<8 * CPX, CF_T, 0, stream>>>(ei, E, NKEY, CPX, gcur, ebin, total_cap);
    sort2<<<NKEY, S2T, 0, stream>>>(ebin, gcur, ebin2, rp16, capk);
    deg_prep<<<NBLKn, 256, 0, stream>>>(rp16, gcur, (const float4*)x, dinv, xs, N, capk);
    l1_fused<<<NBLKn, 256, 0, stream>>>(ebin2, rp16, gcur, xs, dinv, W1, b1, W2, ps, N, capk);
    l2_fused<<<NBLKn, 256, 0, stream>>>(ebin2, rp16, gcur, ps, dinv, b2, (float2*)d_out, N, capk);
}